// Round 1
// baseline (532.904 us; speedup 1.0000x reference)
//
#include <hip/hip_runtime.h>

#define S_LEN 4096
#define D_HEAD 64
#define NH 16
#define C_DIM 1024
#define B_SZ 16
#define NG 256   // B*H groups
#define ATTN_THREADS 512
#define NROWG (ATTN_THREADS / 16)   // 32 row-groups per block

// ---------------------------------------------------------------------------
// Kernel 1: per-group learned-query attention.
// Group g = b*16+h is the contiguous slab K[g*S*d ...] (row-major reshape!),
// query chunk is qnorm[h*64 : h*64+64].
// ---------------------------------------------------------------------------
__global__ __launch_bounds__(ATTN_THREADS) void attn_kernel(
    const float* __restrict__ K, const float* __restrict__ V,
    const float* __restrict__ q, float* __restrict__ A)
{
    const int g   = blockIdx.x;
    const int h   = g & (NH - 1);
    const int tid = threadIdx.x;
    const int sub = tid & 15;   // which float4 within a 64-dim row
    const int rg  = tid >> 4;   // row-group 0..31

    __shared__ float sc[S_LEN];                 // 16 KB scores
    __shared__ float part[NROWG * D_HEAD];      // 8 KB V-pass partials
    __shared__ float red[ATTN_THREADS / 64];    // cross-wave scratch
    __shared__ float s_scalar;                  // qnorm scale
    __shared__ __align__(16) float s_qs[D_HEAD];

    // ---- q norm (redundant per block; q is 4 KB, L2-hot) ----
    float p;
    {
        float a0 = q[tid];
        float a1 = q[tid + ATTN_THREADS];
        p = a0 * a0 + a1 * a1;
    }
    #pragma unroll
    for (int off = 32; off; off >>= 1) p += __shfl_xor(p, off);
    if ((tid & 63) == 0) red[tid >> 6] = p;
    __syncthreads();
    if (tid == 0) {
        float t = 0.f;
        #pragma unroll
        for (int w = 0; w < ATTN_THREADS / 64; w++) t += red[w];
        // combine 1/||q|| with softmax scale 1/sqrt(64) = 0.125
        s_scalar = rsqrtf(t) * 0.125f;
    }
    __syncthreads();
    if (tid < D_HEAD) s_qs[tid] = q[h * D_HEAD + tid] * s_scalar;
    __syncthreads();

    const float4 qv = ((const float4*)s_qs)[sub];
    const float* __restrict__ Kg = K + (size_t)g * (S_LEN * D_HEAD);
    const float* __restrict__ Vg = V + (size_t)g * (S_LEN * D_HEAD);

    // ---- pass 1: scores (16 lanes per row, coalesced float4) ----
    #pragma unroll 4
    for (int r = rg; r < S_LEN; r += NROWG) {
        float4 kv = ((const float4*)(Kg + r * D_HEAD))[sub];
        float d = kv.x * qv.x + kv.y * qv.y + kv.z * qv.z + kv.w * qv.w;
        d += __shfl_xor(d, 1);
        d += __shfl_xor(d, 2);
        d += __shfl_xor(d, 4);
        d += __shfl_xor(d, 8);
        if (sub == 0) sc[r] = d;
    }
    __syncthreads();

    // ---- softmax over 4096 scores ----
    float m = -3.4e38f;
    for (int i = tid; i < S_LEN; i += ATTN_THREADS) m = fmaxf(m, sc[i]);
    #pragma unroll
    for (int off = 32; off; off >>= 1) m = fmaxf(m, __shfl_xor(m, off));
    if ((tid & 63) == 0) red[tid >> 6] = m;
    __syncthreads();
    m = red[0];
    #pragma unroll
    for (int w = 1; w < ATTN_THREADS / 64; w++) m = fmaxf(m, red[w]);
    __syncthreads();   // red about to be reused

    float sum = 0.f;
    for (int i = tid; i < S_LEN; i += ATTN_THREADS) {
        float e = __expf(sc[i] - m);
        sc[i] = e;
        sum += e;
    }
    #pragma unroll
    for (int off = 32; off; off >>= 1) sum += __shfl_xor(sum, off);
    if ((tid & 63) == 0) red[tid >> 6] = sum;
    __syncthreads();
    float denom = 0.f;
    #pragma unroll
    for (int w = 0; w < ATTN_THREADS / 64; w++) denom += red[w];
    const float inv_denom = 1.0f / denom;

    // ---- pass 2: A = attn @ V (same coalesced layout) ----
    float4 acc = make_float4(0.f, 0.f, 0.f, 0.f);
    #pragma unroll 4
    for (int r = rg; r < S_LEN; r += NROWG) {
        float4 vv = ((const float4*)(Vg + r * D_HEAD))[sub];
        float pr = sc[r];   // LDS broadcast
        acc.x += pr * vv.x;
        acc.y += pr * vv.y;
        acc.z += pr * vv.z;
        acc.w += pr * vv.w;
    }
    ((float4*)part)[rg * 16 + sub] = acc;
    __syncthreads();
    if (tid < D_HEAD) {
        float s = 0.f;
        #pragma unroll
        for (int r2 = 0; r2 < NROWG; r2++) s += part[r2 * D_HEAD + tid];
        // A laid out [g][64] == A_full[b][h*64+dd] — exactly the reshape
        A[g * D_HEAD + tid] = s * inv_denom;
    }
}

// ---------------------------------------------------------------------------
// Kernel 2: Y[b,j] = dot(A[b,:], W[j,:]) + bias[j].  One block per column j;
// W row is read coalesced exactly once; A (64 KB) stays hot in L2.
// ---------------------------------------------------------------------------
__global__ __launch_bounds__(256) void proj_kernel(
    const float* __restrict__ A, const float* __restrict__ W,
    const float* __restrict__ bias, float* __restrict__ Y)
{
    const int j = blockIdx.x;
    const int tid = threadIdx.x;
    const float* __restrict__ Wj = W + (size_t)j * C_DIM;

    float acc[B_SZ];
    #pragma unroll
    for (int b = 0; b < B_SZ; b++) acc[b] = 0.f;

    for (int c = tid; c < C_DIM; c += 256) {
        float w = Wj[c];
        #pragma unroll
        for (int b = 0; b < B_SZ; b++) acc[b] += A[b * C_DIM + c] * w;
    }

    __shared__ float redw[B_SZ][4];
    #pragma unroll
    for (int b = 0; b < B_SZ; b++) {
        float v = acc[b];
        #pragma unroll
        for (int off = 32; off; off >>= 1) v += __shfl_xor(v, off);
        if ((tid & 63) == 0) redw[b][tid >> 6] = v;
    }
    __syncthreads();
    if (tid < B_SZ) {
        float s = redw[tid][0] + redw[tid][1] + redw[tid][2] + redw[tid][3];
        Y[tid * C_DIM + j] = s + bias[j];
    }
}

// ---------------------------------------------------------------------------
// Kernel 3: LayerNorm over last dim (1024) per batch row.
// ---------------------------------------------------------------------------
__global__ __launch_bounds__(256) void ln_kernel(
    const float* __restrict__ Y, const float* __restrict__ gam,
    const float* __restrict__ bet, float* __restrict__ out)
{
    const int b = blockIdx.x;
    const int tid = threadIdx.x;
    const float* __restrict__ Yb = Y + b * C_DIM;

    float vals[4];
    float s = 0.f, s2 = 0.f;
    #pragma unroll
    for (int i = 0; i < 4; i++) {
        float v = Yb[tid + i * 256];
        vals[i] = v;
        s += v;
        s2 += v * v;
    }
    #pragma unroll
    for (int off = 32; off; off >>= 1) {
        s  += __shfl_xor(s, off);
        s2 += __shfl_xor(s2, off);
    }
    __shared__ float rs[4], rs2[4];
    if ((tid & 63) == 0) { rs[tid >> 6] = s; rs2[tid >> 6] = s2; }
    __syncthreads();
    s  = rs[0] + rs[1] + rs[2] + rs[3];
    s2 = rs2[0] + rs2[1] + rs2[2] + rs2[3];
    const float mu  = s * (1.0f / C_DIM);
    const float var = s2 * (1.0f / C_DIM) - mu * mu;
    const float inv = rsqrtf(var + 1e-5f);
    #pragma unroll
    for (int i = 0; i < 4; i++) {
        int j = tid + i * 256;
        out[b * C_DIM + j] = gam[j] * (vals[i] - mu) * inv + bet[j];
    }
}

extern "C" void kernel_launch(void* const* d_in, const int* in_sizes, int n_in,
                              void* d_out, int out_size, void* d_ws, size_t ws_size,
                              hipStream_t stream) {
    const float* K    = (const float*)d_in[0];
    const float* V    = (const float*)d_in[1];
    const float* q    = (const float*)d_in[2];
    const float* w0_w = (const float*)d_in[3];
    const float* w0_b = (const float*)d_in[4];
    const float* ln_g = (const float*)d_in[5];
    const float* ln_b = (const float*)d_in[6];

    float* A = (float*)d_ws;            // 16384 floats (64 KB)
    float* Y = A + B_SZ * C_DIM;        // 16384 floats (64 KB)

    attn_kernel<<<NG, ATTN_THREADS, 0, stream>>>(K, V, q, A);
    proj_kernel<<<C_DIM, 256, 0, stream>>>(A, w0_w, w0_b, Y);
    ln_kernel<<<B_SZ, 256, 0, stream>>>(Y, ln_g, ln_b, (float*)d_out);
}

// Round 2
// 524.302 us; speedup vs baseline: 1.0164x; 1.0164x over previous
//
#include <hip/hip_runtime.h>

#define S_LEN 4096
#define D_HEAD 64
#define NH 16
#define C_DIM 1024
#define B_SZ 16
#define NG 256                    // B*H groups
#define NSPLIT 8
#define CHUNK (S_LEN / NSPLIT)    // 512 rows per block
#define TPB 256
#define RG 16                     // row-groups per block (16 lanes each)
#define ITERS (CHUNK / RG)        // 32

// ---------------------------------------------------------------------------
// Kernel 0: normalize q and pre-apply softmax scale: qs = q/||q|| * 0.125
// ---------------------------------------------------------------------------
__global__ __launch_bounds__(256) void qnorm_kernel(
    const float* __restrict__ q, float* __restrict__ qs)
{
    const int tid = threadIdx.x;
    float v[4];
    float p = 0.f;
    #pragma unroll
    for (int i = 0; i < 4; i++) {
        v[i] = q[tid + i * 256];
        p += v[i] * v[i];
    }
    #pragma unroll
    for (int off = 32; off; off >>= 1) p += __shfl_xor(p, off);
    __shared__ float red[4];
    if ((tid & 63) == 0) red[tid >> 6] = p;
    __syncthreads();
    const float total = red[0] + red[1] + red[2] + red[3];
    const float s = rsqrtf(total) * 0.125f;   // 1/||q|| * 1/sqrt(64)
    #pragma unroll
    for (int i = 0; i < 4; i++) qs[tid + i * 256] = v[i] * s;
}

// ---------------------------------------------------------------------------
// Kernel 1: flash-decode partial attention. One block per (group, split):
// local softmax max/sum + unnormalized partial A over a 512-row chunk.
// 2048 blocks x 256 threads -> 8 blocks/CU = 32 waves/CU (full occupancy).
// ---------------------------------------------------------------------------
__global__ __launch_bounds__(TPB) void attn_partial(
    const float* __restrict__ K, const float* __restrict__ V,
    const float* __restrict__ qs, float* __restrict__ Apart,
    float* __restrict__ mArr, float* __restrict__ lArr)
{
    const int blk   = blockIdx.x;
    const int g     = blk >> 3;       // group 0..255
    const int split = blk & 7;        // chunk 0..7
    const int h     = g & (NH - 1);
    const int tid   = threadIdx.x;
    const int sub   = tid & 15;       // float4 index within 64-dim row
    const int rg    = tid >> 4;       // row-group 0..15

    __shared__ float sc[CHUNK];                     // 2 KB scores
    __shared__ __align__(16) float part[RG * D_HEAD]; // 4 KB V partials
    __shared__ float red[TPB / 64];

    const float4 qv = ((const float4*)(qs + h * D_HEAD))[sub];
    const float* __restrict__ Kg = K + ((size_t)g * S_LEN + (size_t)split * CHUNK) * D_HEAD;
    const float* __restrict__ Vg = V + ((size_t)g * S_LEN + (size_t)split * CHUNK) * D_HEAD;

    // ---- pass 1: scores over this chunk (coalesced float4, 16 lanes/row) ----
    #pragma unroll 8
    for (int i = 0; i < ITERS; i++) {
        const int r = rg + i * RG;
        float4 kv = ((const float4*)(Kg + r * D_HEAD))[sub];
        float d = kv.x * qv.x + kv.y * qv.y + kv.z * qv.z + kv.w * qv.w;
        d += __shfl_xor(d, 1);
        d += __shfl_xor(d, 2);
        d += __shfl_xor(d, 4);
        d += __shfl_xor(d, 8);
        if (sub == 0) sc[r] = d;
    }
    __syncthreads();

    // ---- local max ----
    float m = fmaxf(sc[tid], sc[tid + 256]);
    #pragma unroll
    for (int off = 32; off; off >>= 1) m = fmaxf(m, __shfl_xor(m, off));
    if ((tid & 63) == 0) red[tid >> 6] = m;
    __syncthreads();
    m = fmaxf(fmaxf(red[0], red[1]), fmaxf(red[2], red[3]));
    __syncthreads();   // red reused below

    // ---- exp + local sum ----
    const float e0 = __expf(sc[tid] - m);
    const float e1 = __expf(sc[tid + 256] - m);
    sc[tid] = e0;
    sc[tid + 256] = e1;
    float sum = e0 + e1;
    #pragma unroll
    for (int off = 32; off; off >>= 1) sum += __shfl_xor(sum, off);
    if ((tid & 63) == 0) red[tid >> 6] = sum;
    __syncthreads();
    const float lsum = red[0] + red[1] + red[2] + red[3];

    // ---- pass 2: unnormalized partial A = exp(sc) @ Vchunk ----
    float4 acc = make_float4(0.f, 0.f, 0.f, 0.f);
    #pragma unroll 8
    for (int i = 0; i < ITERS; i++) {
        const int r = rg + i * RG;
        float4 vv = ((const float4*)(Vg + r * D_HEAD))[sub];
        const float pr = sc[r];   // LDS broadcast within row-group
        acc.x += pr * vv.x;
        acc.y += pr * vv.y;
        acc.z += pr * vv.z;
        acc.w += pr * vv.w;
    }
    ((float4*)part)[rg * 16 + sub] = acc;
    __syncthreads();
    if (tid < D_HEAD) {
        float s = 0.f;
        #pragma unroll
        for (int r2 = 0; r2 < RG; r2++) s += part[r2 * D_HEAD + tid];
        Apart[(size_t)blk * D_HEAD + tid] = s;
    }
    if (tid == 0) {
        mArr[blk] = m;
        lArr[blk] = lsum;
    }
}

// ---------------------------------------------------------------------------
// Kernel 2: online-softmax merge of the 8 splits per group.
// ---------------------------------------------------------------------------
__global__ __launch_bounds__(64) void attn_combine(
    const float* __restrict__ Apart, const float* __restrict__ mArr,
    const float* __restrict__ lArr, float* __restrict__ A)
{
    const int g = blockIdx.x;
    const int d = threadIdx.x;
    float mv[NSPLIT];
    float M = -3.4e38f;
    #pragma unroll
    for (int s = 0; s < NSPLIT; s++) {
        mv[s] = mArr[g * NSPLIT + s];
        M = fmaxf(M, mv[s]);
    }
    float denom = 0.f, acc = 0.f;
    #pragma unroll
    for (int s = 0; s < NSPLIT; s++) {
        const float f = __expf(mv[s] - M);
        denom += f * lArr[g * NSPLIT + s];
        acc   += f * Apart[(size_t)(g * NSPLIT + s) * D_HEAD + d];
    }
    A[g * D_HEAD + d] = acc / denom;   // layout == A_full[b][h*64+d]
}

// ---------------------------------------------------------------------------
// Kernel 3: Y[b,j] = dot(A[b,:], W[j,:]) + bias[j]. One block per column j.
// ---------------------------------------------------------------------------
__global__ __launch_bounds__(256) void proj_kernel(
    const float* __restrict__ A, const float* __restrict__ W,
    const float* __restrict__ bias, float* __restrict__ Y)
{
    const int j = blockIdx.x;
    const int tid = threadIdx.x;
    const float* __restrict__ Wj = W + (size_t)j * C_DIM;

    float acc[B_SZ];
    #pragma unroll
    for (int b = 0; b < B_SZ; b++) acc[b] = 0.f;

    #pragma unroll
    for (int k = 0; k < 4; k++) {
        const int c = tid + k * 256;
        const float w = Wj[c];
        #pragma unroll
        for (int b = 0; b < B_SZ; b++) acc[b] += A[b * C_DIM + c] * w;
    }

    __shared__ float redw[B_SZ][4];
    #pragma unroll
    for (int b = 0; b < B_SZ; b++) {
        float v = acc[b];
        #pragma unroll
        for (int off = 32; off; off >>= 1) v += __shfl_xor(v, off);
        if ((tid & 63) == 0) redw[b][tid >> 6] = v;
    }
    __syncthreads();
    if (tid < B_SZ) {
        const float s = redw[tid][0] + redw[tid][1] + redw[tid][2] + redw[tid][3];
        Y[tid * C_DIM + j] = s + bias[j];
    }
}

// ---------------------------------------------------------------------------
// Kernel 4: LayerNorm over last dim (1024) per batch row.
// ---------------------------------------------------------------------------
__global__ __launch_bounds__(256) void ln_kernel(
    const float* __restrict__ Y, const float* __restrict__ gam,
    const float* __restrict__ bet, float* __restrict__ out)
{
    const int b = blockIdx.x;
    const int tid = threadIdx.x;
    const float* __restrict__ Yb = Y + b * C_DIM;

    float vals[4];
    float s = 0.f, s2 = 0.f;
    #pragma unroll
    for (int i = 0; i < 4; i++) {
        const float v = Yb[tid + i * 256];
        vals[i] = v;
        s += v;
        s2 += v * v;
    }
    #pragma unroll
    for (int off = 32; off; off >>= 1) {
        s  += __shfl_xor(s, off);
        s2 += __shfl_xor(s2, off);
    }
    __shared__ float rs[4], rs2[4];
    if ((tid & 63) == 0) { rs[tid >> 6] = s; rs2[tid >> 6] = s2; }
    __syncthreads();
    s  = rs[0] + rs[1] + rs[2] + rs[3];
    s2 = rs2[0] + rs2[1] + rs2[2] + rs2[3];
    const float mu  = s * (1.0f / C_DIM);
    const float var = s2 * (1.0f / C_DIM) - mu * mu;
    const float inv = rsqrtf(var + 1e-5f);
    #pragma unroll
    for (int i = 0; i < 4; i++) {
        const int j = tid + i * 256;
        out[b * C_DIM + j] = gam[j] * (vals[i] - mu) * inv + bet[j];
    }
}

extern "C" void kernel_launch(void* const* d_in, const int* in_sizes, int n_in,
                              void* d_out, int out_size, void* d_ws, size_t ws_size,
                              hipStream_t stream) {
    const float* K    = (const float*)d_in[0];
    const float* V    = (const float*)d_in[1];
    const float* q    = (const float*)d_in[2];
    const float* w0_w = (const float*)d_in[3];
    const float* w0_b = (const float*)d_in[4];
    const float* ln_g = (const float*)d_in[5];
    const float* ln_b = (const float*)d_in[6];

    float* qs    = (float*)d_ws;                      // 1024
    float* Apart = qs + C_DIM;                        // 2048*64 = 131072
    float* mArr  = Apart + (size_t)NG * NSPLIT * D_HEAD; // 2048
    float* lArr  = mArr + NG * NSPLIT;                // 2048
    float* A     = lArr + NG * NSPLIT;                // 16384
    float* Y     = A + B_SZ * C_DIM;                  // 16384

    qnorm_kernel<<<1, 256, 0, stream>>>(q, qs);
    attn_partial<<<NG * NSPLIT, TPB, 0, stream>>>(K, V, qs, Apart, mArr, lArr);
    attn_combine<<<NG, 64, 0, stream>>>(Apart, mArr, lArr, A);
    proj_kernel<<<C_DIM, 256, 0, stream>>>(A, w0_w, w0_b, Y);
    ln_kernel<<<B_SZ, 256, 0, stream>>>(Y, ln_g, ln_b, (float*)d_out);
}